// Round 6
// baseline (298.135 us; speedup 1.0000x reference)
//
#include <hip/hip_runtime.h>
#include <hip/hip_bf16.h>
#include <math.h>

#define EPS 1e-8f

typedef __attribute__((ext_vector_type(8))) short short8;
typedef __attribute__((ext_vector_type(16))) float floatx16;
typedef unsigned short ushort_t;

#define GPTR(p) ((const __attribute__((address_space(1))) void*)(p))
#define LPTR(p) ((__attribute__((address_space(3))) void*)(p))

__device__ __forceinline__ unsigned short f2bf(float f) {
  unsigned int u = __float_as_uint(f);
  u += 0x7FFFu + ((u >> 16) & 1u);   // RNE
  return (unsigned short)(u >> 16);
}

// ---------------- kA: per-speaker column sums -> sums_bf, ss, rcn ----------
__global__ __launch_bounds__(256) void kA(const float* __restrict__ x,
    ushort_t* __restrict__ sums_bf, float* __restrict__ ss,
    float* __restrict__ rcn, const float* __restrict__ wp) {
  const int n = blockIdx.x;
  const int t = threadIdx.x;
  const float* xp = x + (size_t)n * (64 * 768);
  float s0 = 0.f, s1 = 0.f, s2 = 0.f;
#pragma unroll 8
  for (int m = 0; m < 64; ++m) {
    const float* r = xp + m * 768;
    s0 += r[t]; s1 += r[t + 256]; s2 += r[t + 512];
  }
  ushort_t* sb = sums_bf + (size_t)n * 768;
  sb[t] = f2bf(s0); sb[t + 256] = f2bf(s1); sb[t + 512] = f2bf(s2);
  float lss = s0 * s0 + s1 * s1 + s2 * s2;
  for (int o = 32; o; o >>= 1) lss += __shfl_xor(lss, o, 64);
  __shared__ float red[4];
  if ((t & 63) == 0) red[t >> 6] = lss;
  __syncthreads();
  if (t == 0) {
    const float v = red[0] + red[1] + red[2] + red[3];
    ss[n] = v;
    rcn[n] = (*wp) / fmaxf(sqrtf(v), 64.f * EPS);  // w / (M * cn)
  }
}

// ---------------- kC: MFMA GEMM + exp-colsum + diag terms ------------------
// 512 blocks x 256 thr (4 waves x 32 j = 128 j per block; n-split 2: 256 n).
// A (sums_bf) frag-major LDS via global_load_lds (zero bank conflicts),
// dbuf half-K tiles (2 x 24KB), __syncthreads pipeline (spill-robust).
// B (x) in regs: 48 bf16x8 frags = full K=768.
__global__ __launch_bounds__(256, 2) void kC(const float* __restrict__ x,
    const ushort_t* __restrict__ sums_bf, const float* __restrict__ rcn,
    const float* __restrict__ ss, const float* __restrict__ wp,
    const float* __restrict__ bp, float* __restrict__ colsum,
    float* __restrict__ ssame, float* __restrict__ sdiag) {
  __shared__ ushort_t Abuf[2][12288];   // 2 x 24KB = 32 n-rows x 384 k, frag-major
  const int bid = blockIdx.x;
  const int jb = (bid >> 4) * 8 + (bid & 7);   // XCD twin pairing: bid, bid+8 share jb
  const int nb = (bid >> 3) & 1;
  const int t = threadIdx.x;
  const int wv = t >> 6;
  const int l = t & 63;
  const int hi = l >> 5;
  const int jw0 = jb * 128 + wv * 32;
  const int jcol = jw0 + (l & 31);
  const int i0 = jw0 >> 6;              // wave-uniform speaker index

// stage half-K tile HT_ (n-tile HT_>>1, K-half HT_&1) -> buf HT_&1; 6 loads/wave
#define STAGE(HT_)                                                             \
  if ((HT_) < 16) {                                                            \
    const ushort_t* gb_ = sums_bf +                                            \
        (size_t)((nb * 8 + ((HT_) >> 1)) * 32 + (l & 31)) * 768 +              \
        ((HT_) & 1) * 384 + hi * 8;                                            \
    _Pragma("unroll")                                                          \
    for (int i_ = 0; i_ < 6; ++i_) {                                           \
      const int fi_ = wv * 6 + i_;                                             \
      __builtin_amdgcn_global_load_lds(GPTR(gb_ + fi_ * 16),                   \
          LPTR(&Abuf[(HT_) & 1][fi_ * 512]), 16, 0, 0);                        \
    }                                                                          \
  }

#define COMPUTE(BUF_, KH_)                                                     \
  _Pragma("unroll")                                                            \
  for (int kk_ = 0; kk_ < 24; ++kk_) {                                         \
    short8 af_ = *(const short8*)&Abuf[BUF_][kk_ * 512 + l * 8];               \
    acc = __builtin_amdgcn_mfma_f32_32x32x16_bf16(af_, bfr[(KH_) * 24 + kk_],  \
                                                  acc, 0, 0, 0);               \
  }

  STAGE(0)   // overlaps with B prologue below

  // ---- B prologue: x rows -> bf16 frags; row norm xx in fp32
  short8 bfr[48];
  float xx2 = 0.f;
  {
    const float* xrow = x + (size_t)jcol * 768;
#pragma unroll
    for (int kk = 0; kk < 48; ++kk) {
      const float* p = xrow + kk * 16 + hi * 8;
      float4 u0 = *(const float4*)p;
      float4 u1 = *(const float4*)(p + 4);
      xx2 += u0.x * u0.x + u0.y * u0.y + u0.z * u0.z + u0.w * u0.w
           + u1.x * u1.x + u1.y * u1.y + u1.z * u1.z + u1.w * u1.w;
      short8 r;
      r[0] = (short)f2bf(u0.x); r[1] = (short)f2bf(u0.y);
      r[2] = (short)f2bf(u0.z); r[3] = (short)f2bf(u0.w);
      r[4] = (short)f2bf(u1.x); r[5] = (short)f2bf(u1.y);
      r[6] = (short)f2bf(u1.z); r[7] = (short)f2bf(u1.w);
      bfr[kk] = r;
    }
  }
  const float xx_tot = xx2 + __shfl_xor(xx2, 32, 64);
  const float xn = fmaxf(sqrtf(xx_tot), EPS);
  const float rx = 1.f / xn;
  const float ww = *wp, bb = *bp;

  floatx16 acc;
#pragma unroll
  for (int r = 0; r < 16; ++r) acc[r] = 0.f;
  float colp = 0.f;
  float sxl = 0.f;

  __syncthreads();                       // tile 0 staged & drained

  for (int ht = 0; ht < 16; ++ht) {
    STAGE(ht + 1)                        // issue next half-tile (overlaps MFMA)
    COMPUTE(ht & 1, ht & 1)
    if (ht & 1) {
      // epilogue for n-tile nt = ht>>1
      const int nt = ht >> 1;
      const float* rc = rcn + (nb * 8 + nt) * 32;
#pragma unroll
      for (int r = 0; r < 16; ++r) {
        const int row = (r & 3) + 8 * (r >> 2) + 4 * hi;
        colp += __expf(acc[r] * rc[row] * rx + bb);
      }
      if ((i0 >> 5) == nb * 8 + nt) {    // diagonal tile: sx = dot(sums_i, x_j)
        const int r0 = i0 & 31;
        const int tgt_hi = (r0 >> 2) & 1;
        const int tgt_r = 4 * (r0 >> 3) + (r0 & 3);
        float sxv = 0.f;
#pragma unroll
        for (int r = 0; r < 16; ++r) if (r == tgt_r) sxv = acc[r];
        const float o = __shfl_xor(sxv, 32, 64);
        sxl = (hi == tgt_hi) ? sxv : o;
      }
#pragma unroll
      for (int r = 0; r < 16; ++r) acc[r] = 0.f;
    }
    __syncthreads();                     // drains stage(ht+1); readers done with buf
  }

  // ---- tail: column-sum atomics + diagonal terms
  colp += __shfl_xor(colp, 32, 64);      // combine the two row-halves (hi groups)
  if (l < 32) atomicAdd(&colsum[jcol], colp);

  if ((i0 >> 8) == nb) {                 // the twin whose n-range holds speaker i0
    const float ssi = ss[i0];
    const float sd = sxl * rcn[i0] * rx + bb;                   // S_diag
    const float exn = sqrtf(fmaxf(ssi - 2.f * sxl + xx_tot, 0.f)) * (1.f / 63.f);
    const float edot = (sxl - xx_tot) * (1.f / 63.f);
    const float sm = ww * edot / (fmaxf(exn, EPS) * xn) + bb;   // S_same
    if (l < 32) { ssame[jcol] = sm; sdiag[jcol] = sd; }
  }
}

// ---------------- kD: per-sample loss + reduce -----------------------------
__global__ __launch_bounds__(256) void kD(const float* __restrict__ colsum,
    const float* __restrict__ ssame, const float* __restrict__ sdiag,
    float* __restrict__ out) {
  const int j = blockIdx.x * 256 + threadIdx.x;
  const float sm = ssame[j];
  const float tot = colsum[j] - __expf(sdiag[j]) + __expf(sm);
  float L = -sm + logf(fmaxf(tot, 1e-30f));
  for (int o = 32; o; o >>= 1) L += __shfl_xor(L, o, 64);
  __shared__ float red[4];
  if ((threadIdx.x & 63) == 0) red[threadIdx.x >> 6] = L;
  __syncthreads();
  if (threadIdx.x == 0) atomicAdd(out, red[0] + red[1] + red[2] + red[3]);
}

extern "C" void kernel_launch(void* const* d_in, const int* in_sizes, int n_in,
                              void* d_out, int out_size, void* d_ws, size_t ws_size,
                              hipStream_t stream) {
  const float* x  = (const float*)d_in[0];
  const float* wp = (const float*)d_in[1];
  const float* bp = (const float*)d_in[2];
  float* out = (float*)d_out;

  // ws layout: sums_bf = 512*768 = 393216 ushorts = 196608 float-equivalents
  ushort_t* sums_bf = (ushort_t*)d_ws;
  float* fws    = (float*)d_ws;
  float* ss     = fws + 196608;
  float* rcn    = fws + 197120;
  float* colsum = fws + 197632;
  float* ssame  = fws + 230400;
  float* sdiag  = fws + 263168;   // end @ 295936 floats = 1.18 MB

  hipMemsetAsync(colsum, 0, 32768 * sizeof(float), stream);
  hipMemsetAsync(out, 0, sizeof(float), stream);

  kA<<<512, 256, 0, stream>>>(x, sums_bf, ss, rcn, wp);
  kC<<<512, 256, 0, stream>>>(x, sums_bf, rcn, ss, wp, bp, colsum, ssame, sdiag);
  kD<<<128, 256, 0, stream>>>(colsum, ssame, sdiag, out);
}

// Round 7
// 91.575 us; speedup vs baseline: 3.2556x; 3.2556x over previous
//
#include <hip/hip_runtime.h>
#include <hip/hip_bf16.h>
#include <math.h>

#define EPS 1e-8f

typedef __attribute__((ext_vector_type(8))) short short8;
typedef __attribute__((ext_vector_type(4))) float floatx4;
typedef unsigned short ushort_t;

#define GPTR(p) ((const __attribute__((address_space(1))) void*)(p))
#define LPTR(p) ((__attribute__((address_space(3))) void*)(p))

__device__ __forceinline__ unsigned short f2bf(float f) {
  unsigned int u = __float_as_uint(f);
  u += 0x7FFFu + ((u >> 16) & 1u);   // RNE
  return (unsigned short)(u >> 16);
}
__device__ __forceinline__ unsigned int pack2bf(float a, float b) {
  return (unsigned int)f2bf(a) | ((unsigned int)f2bf(b) << 16);
}

// ---- kA: one speaker per block. x -> x_bf, row norms (xx, rxn),
//          column sums -> sums_bf, ss, rcn. Single 96MB pass over x.
__global__ __launch_bounds__(256) void kA(const float* __restrict__ x,
    ushort_t* __restrict__ xbf, ushort_t* __restrict__ sums_bf,
    float* __restrict__ ss, float* __restrict__ rcn,
    float* __restrict__ xx, float* __restrict__ rxn,
    const float* __restrict__ wp) {
  const int n = blockIdx.x;
  const int t = threadIdx.x;
  const int wv = t >> 6, l = t & 63;
  __shared__ float csum[4][768];   // 12 KB
  float4 cs0 = {0,0,0,0}, cs1 = {0,0,0,0}, cs2 = {0,0,0,0};

  for (int r = 0; r < 16; ++r) {
    const int row = wv * 16 + r;
    const size_t base = ((size_t)n * 64 + row) * 768;
    const float* rp = x + base;
    float4 v0 = *(const float4*)(rp + l * 4);
    float4 v1 = *(const float4*)(rp + l * 4 + 256);
    float4 v2 = *(const float4*)(rp + l * 4 + 512);
    uint2 b0 = { pack2bf(v0.x, v0.y), pack2bf(v0.z, v0.w) };
    uint2 b1 = { pack2bf(v1.x, v1.y), pack2bf(v1.z, v1.w) };
    uint2 b2 = { pack2bf(v2.x, v2.y), pack2bf(v2.z, v2.w) };
    *(uint2*)(xbf + base + l * 4)       = b0;
    *(uint2*)(xbf + base + l * 4 + 256) = b1;
    *(uint2*)(xbf + base + l * 4 + 512) = b2;
    float rq = v0.x*v0.x + v0.y*v0.y + v0.z*v0.z + v0.w*v0.w
             + v1.x*v1.x + v1.y*v1.y + v1.z*v1.z + v1.w*v1.w
             + v2.x*v2.x + v2.y*v2.y + v2.z*v2.z + v2.w*v2.w;
    for (int o = 32; o; o >>= 1) rq += __shfl_xor(rq, o, 64);
    if (l == 0) {
      const int j = n * 64 + row;
      xx[j] = rq;
      rxn[j] = 1.0f / fmaxf(sqrtf(rq), EPS);
    }
    cs0.x += v0.x; cs0.y += v0.y; cs0.z += v0.z; cs0.w += v0.w;
    cs1.x += v1.x; cs1.y += v1.y; cs1.z += v1.z; cs1.w += v1.w;
    cs2.x += v2.x; cs2.y += v2.y; cs2.z += v2.z; cs2.w += v2.w;
  }
  *(float4*)&csum[wv][l * 4]       = cs0;
  *(float4*)&csum[wv][l * 4 + 256] = cs1;
  *(float4*)&csum[wv][l * 4 + 512] = cs2;
  __syncthreads();

  float lss = 0.f;
#pragma unroll
  for (int q = 0; q < 3; ++q) {
    const int c = t + q * 256;
    const float s = csum[0][c] + csum[1][c] + csum[2][c] + csum[3][c];
    sums_bf[(size_t)n * 768 + c] = f2bf(s);
    lss += s * s;
  }
  for (int o = 32; o; o >>= 1) lss += __shfl_xor(lss, o, 64);
  __syncthreads();
  if (l == 0) csum[1][wv] = lss;   // reuse LDS slot
  __syncthreads();
  if (t == 0) {
    const float v = csum[1][0] + csum[1][1] + csum[1][2] + csum[1][3];
    ss[n] = v;
    rcn[n] = (*wp) / fmaxf(sqrtf(v), 64.f * EPS);   // w / (M * cn)
  }
}

// ---- kC: m97-pattern MFMA GEMM, tile 128n x 128j, BK=32, 4 waves (64x64 each).
// Both A (sums_bf) and B (x_bf) staged frag-major via global_load_lds.
// Fused epilogue: exp + colsum atomics + diagonal sx extraction.
__global__ __launch_bounds__(256) void kC(const ushort_t* __restrict__ xbf,
    const ushort_t* __restrict__ sums_bf, const float* __restrict__ rcn,
    const float* __restrict__ rxn, float* __restrict__ colsum,
    float* __restrict__ sdiag_dot, const float* __restrict__ bp) {
  __shared__ ushort_t Ab[2][4096];   // 2 x 8KB: 8 frags of 512 ushorts
  __shared__ ushort_t Bb[2][4096];
  const int b = blockIdx.x;
  const int xcd = b & 7;
  const int inner = b >> 3;
  const int nt = inner & 3;                      // 4 n-blocks of a j-tile on same XCD
  const int jt = xcd + ((inner >> 2) << 3);
  const int n0 = nt * 128, j0 = jt * 128;
  const int t = threadIdx.x, wv = t >> 6, l = t & 63;
  const int wm = wv >> 1, wj = wv & 1;

#define STAGE(KS_, BUF_) {                                                     \
    const int k0_ = (KS_) * 32;                                                \
    const ushort_t* As_ = sums_bf + (size_t)(n0 + (l & 15)) * 768 + k0_ + (l >> 4) * 8; \
    const ushort_t* Bs_ = xbf + (size_t)(j0 + (l & 15)) * 768 + k0_ + (l >> 4) * 8;     \
    __builtin_amdgcn_global_load_lds(GPTR(As_ + (size_t)wv * (16 * 768)),      \
        LPTR(&Ab[BUF_][wv * 512]), 16, 0, 0);                                  \
    __builtin_amdgcn_global_load_lds(GPTR(As_ + (size_t)(wv + 4) * (16 * 768)),\
        LPTR(&Ab[BUF_][(wv + 4) * 512]), 16, 0, 0);                            \
    __builtin_amdgcn_global_load_lds(GPTR(Bs_ + (size_t)wv * (16 * 768)),      \
        LPTR(&Bb[BUF_][wv * 512]), 16, 0, 0);                                  \
    __builtin_amdgcn_global_load_lds(GPTR(Bs_ + (size_t)(wv + 4) * (16 * 768)),\
        LPTR(&Bb[BUF_][(wv + 4) * 512]), 16, 0, 0);                            \
  }

  floatx4 acc[4][4];
#pragma unroll
  for (int mi = 0; mi < 4; ++mi)
#pragma unroll
    for (int ni = 0; ni < 4; ++ni) acc[mi][ni] = (floatx4){0.f, 0.f, 0.f, 0.f};

  STAGE(0, 0)
  __syncthreads();

  for (int ks = 0; ks < 24; ++ks) {
    if (ks < 23) STAGE(ks + 1, (ks + 1) & 1)
    short8 af[4], bfv[4];
#pragma unroll
    for (int mi = 0; mi < 4; ++mi)
      af[mi] = *(const short8*)&Ab[ks & 1][(wm * 4 + mi) * 512 + l * 8];
#pragma unroll
    for (int ni = 0; ni < 4; ++ni)
      bfv[ni] = *(const short8*)&Bb[ks & 1][(wj * 4 + ni) * 512 + l * 8];
#pragma unroll
    for (int mi = 0; mi < 4; ++mi)
#pragma unroll
      for (int ni = 0; ni < 4; ++ni)
        acc[mi][ni] = __builtin_amdgcn_mfma_f32_16x16x32_bf16(
            af[mi], bfv[ni], acc[mi][ni], 0, 0, 0);
    __syncthreads();
  }

  // ---- epilogue: S = acc * rcn[n] * rxn[j] + b ; colsum += exp(S); diag sx.
  const float bb = *bp;
  float rcv[16], rxv[4], p[4] = {0.f, 0.f, 0.f, 0.f};
#pragma unroll
  for (int mi = 0; mi < 4; ++mi) {
    float4 rr = *(const float4*)&rcn[n0 + wm * 64 + mi * 16 + ((l >> 4) << 2)];
    rcv[mi * 4 + 0] = rr.x; rcv[mi * 4 + 1] = rr.y;
    rcv[mi * 4 + 2] = rr.z; rcv[mi * 4 + 3] = rr.w;
  }
#pragma unroll
  for (int ni = 0; ni < 4; ++ni)
    rxv[ni] = rxn[j0 + wj * 64 + ni * 16 + (l & 15)];
  const bool diagblk = (nt == (jt >> 6));

#pragma unroll
  for (int mi = 0; mi < 4; ++mi)
#pragma unroll
    for (int ni = 0; ni < 4; ++ni) {
      floatx4 a = acc[mi][ni];
#pragma unroll
      for (int q = 0; q < 4; ++q)
        p[ni] += __expf(a[q] * rcv[mi * 4 + q] * rxv[ni] + bb);
      if (diagblk) {
        const int jg = j0 + wj * 64 + ni * 16 + (l & 15);
#pragma unroll
        for (int q = 0; q < 4; ++q) {
          const int mg = n0 + wm * 64 + mi * 16 + ((l >> 4) << 2) + q;
          if (mg == (jg >> 6)) sdiag_dot[jg] = a[q];
        }
      }
    }
#pragma unroll
  for (int ni = 0; ni < 4; ++ni) {
    p[ni] += __shfl_xor(p[ni], 16, 64);
    p[ni] += __shfl_xor(p[ni], 32, 64);
  }
  if (l < 16) {
#pragma unroll
    for (int ni = 0; ni < 4; ++ni)
      atomicAdd(&colsum[j0 + wj * 64 + ni * 16 + l], p[ni]);
  }
}

// ---- kD: per-sample loss from colsum + diagonal dot, reduce to scalar -----
__global__ __launch_bounds__(256) void kD(const float* __restrict__ colsum,
    const float* __restrict__ sdiag_dot, const float* __restrict__ xx,
    const float* __restrict__ ss, const float* __restrict__ rcn,
    const float* __restrict__ wp, const float* __restrict__ bp,
    float* __restrict__ out) {
  const int j = blockIdx.x * 256 + threadIdx.x;
  const int i = j >> 6;
  const float ww = *wp, bb = *bp;
  const float sx = sdiag_dot[j];
  const float xxv = xx[j];
  const float xn = fmaxf(sqrtf(xxv), EPS);
  const float rx = 1.0f / xn;
  const float sd = sx * rcn[i] * rx + bb;                         // S_diag
  const float exn = sqrtf(fmaxf(ss[i] - 2.f * sx + xxv, 0.f)) * (1.f / 63.f);
  const float edot = (sx - xxv) * (1.f / 63.f);
  const float sm = ww * edot / (fmaxf(exn, EPS) * xn) + bb;       // S_same
  const float tot = colsum[j] - __expf(sd) + __expf(sm);
  float L = -sm + logf(fmaxf(tot, 1e-30f));
  for (int o = 32; o; o >>= 1) L += __shfl_xor(L, o, 64);
  __shared__ float red[4];
  if ((threadIdx.x & 63) == 0) red[threadIdx.x >> 6] = L;
  __syncthreads();
  if (threadIdx.x == 0) atomicAdd(out, red[0] + red[1] + red[2] + red[3]);
}

extern "C" void kernel_launch(void* const* d_in, const int* in_sizes, int n_in,
                              void* d_out, int out_size, void* d_ws, size_t ws_size,
                              hipStream_t stream) {
  const float* x  = (const float*)d_in[0];
  const float* wp = (const float*)d_in[1];
  const float* bp = (const float*)d_in[2];
  float* out = (float*)d_out;

  // ws layout (float offsets):
  float* fws = (float*)d_ws;
  float* ss        = fws;             // 512
  float* rcn       = fws + 512;       // 512
  float* xx        = fws + 1024;      // 32768
  float* rxn       = fws + 33792;     // 32768
  float* colsum    = fws + 66560;     // 32768
  float* sdiag_dot = fws + 99328;     // 32768
  ushort_t* sums_bf = (ushort_t*)(fws + 132096);   // 393216 ushorts
  ushort_t* xbf     = (ushort_t*)(fws + 328704);   // 25165824 ushorts
  // total = 12911616 floats ~= 49.3 MiB

  hipMemsetAsync(colsum, 0, 32768 * sizeof(float), stream);
  hipMemsetAsync(out, 0, sizeof(float), stream);

  kA<<<512, 256, 0, stream>>>(x, xbf, sums_bf, ss, rcn, xx, rxn, wp);
  kC<<<1024, 256, 0, stream>>>(xbf, sums_bf, rcn, rxn, colsum, sdiag_dot, bp);
  kD<<<128, 256, 0, stream>>>(colsum, sdiag_dot, xx, ss, rcn, wp, bp, out);
}

// Round 8
// 86.987 us; speedup vs baseline: 3.4274x; 1.0528x over previous
//
#include <hip/hip_runtime.h>
#include <hip/hip_bf16.h>
#include <math.h>

#define EPS 1e-8f

typedef __attribute__((ext_vector_type(8))) short short8;
typedef __attribute__((ext_vector_type(4))) float floatx4;
typedef unsigned short ushort_t;

#define GPTR(p) ((const __attribute__((address_space(1))) void*)(p))
#define LPTR(p) ((__attribute__((address_space(3))) void*)(p))

__device__ __forceinline__ unsigned short f2bf(float f) {
  unsigned int u = __float_as_uint(f);
  u += 0x7FFFu + ((u >> 16) & 1u);   // RNE
  return (unsigned short)(u >> 16);
}
__device__ __forceinline__ unsigned int pack2bf(float a, float b) {
  return (unsigned int)f2bf(a) | ((unsigned int)f2bf(b) << 16);
}

// ---- kA: one speaker per block. x -> x_bf, row norms (xx, rxn),
//          column sums -> sums_bf, ss, rcn. Single 96MB pass over x.
__global__ __launch_bounds__(256) void kA(const float* __restrict__ x,
    ushort_t* __restrict__ xbf, ushort_t* __restrict__ sums_bf,
    float* __restrict__ ss, float* __restrict__ rcn,
    float* __restrict__ xx, float* __restrict__ rxn,
    const float* __restrict__ wp) {
  const int n = blockIdx.x;
  const int t = threadIdx.x;
  const int wv = t >> 6, l = t & 63;
  __shared__ float csum[4][768];   // 12 KB
  float4 cs0 = {0,0,0,0}, cs1 = {0,0,0,0}, cs2 = {0,0,0,0};

  for (int r = 0; r < 16; ++r) {
    const int row = wv * 16 + r;
    const size_t base = ((size_t)n * 64 + row) * 768;
    const float* rp = x + base;
    float4 v0 = *(const float4*)(rp + l * 4);
    float4 v1 = *(const float4*)(rp + l * 4 + 256);
    float4 v2 = *(const float4*)(rp + l * 4 + 512);
    uint2 b0 = { pack2bf(v0.x, v0.y), pack2bf(v0.z, v0.w) };
    uint2 b1 = { pack2bf(v1.x, v1.y), pack2bf(v1.z, v1.w) };
    uint2 b2 = { pack2bf(v2.x, v2.y), pack2bf(v2.z, v2.w) };
    *(uint2*)(xbf + base + l * 4)       = b0;
    *(uint2*)(xbf + base + l * 4 + 256) = b1;
    *(uint2*)(xbf + base + l * 4 + 512) = b2;
    float rq = v0.x*v0.x + v0.y*v0.y + v0.z*v0.z + v0.w*v0.w
             + v1.x*v1.x + v1.y*v1.y + v1.z*v1.z + v1.w*v1.w
             + v2.x*v2.x + v2.y*v2.y + v2.z*v2.z + v2.w*v2.w;
    for (int o = 32; o; o >>= 1) rq += __shfl_xor(rq, o, 64);
    if (l == 0) {
      const int j = n * 64 + row;
      xx[j] = rq;
      rxn[j] = 1.0f / fmaxf(sqrtf(rq), EPS);
    }
    cs0.x += v0.x; cs0.y += v0.y; cs0.z += v0.z; cs0.w += v0.w;
    cs1.x += v1.x; cs1.y += v1.y; cs1.z += v1.z; cs1.w += v1.w;
    cs2.x += v2.x; cs2.y += v2.y; cs2.z += v2.z; cs2.w += v2.w;
  }
  *(float4*)&csum[wv][l * 4]       = cs0;
  *(float4*)&csum[wv][l * 4 + 256] = cs1;
  *(float4*)&csum[wv][l * 4 + 512] = cs2;
  __syncthreads();

  float lss = 0.f;
#pragma unroll
  for (int q = 0; q < 3; ++q) {
    const int c = t + q * 256;
    const float s = csum[0][c] + csum[1][c] + csum[2][c] + csum[3][c];
    sums_bf[(size_t)n * 768 + c] = f2bf(s);
    lss += s * s;
  }
  for (int o = 32; o; o >>= 1) lss += __shfl_xor(lss, o, 64);
  __syncthreads();
  if (l == 0) csum[1][wv] = lss;   // reuse LDS slot
  __syncthreads();
  if (t == 0) {
    const float v = csum[1][0] + csum[1][1] + csum[1][2] + csum[1][3];
    ss[n] = v;
    rcn[n] = (*wp) / fmaxf(sqrtf(v), 64.f * EPS);   // w / (M * cn)
  }
}

// ---- kC: MFMA GEMM 128n x 128j, BK=32, triple-buffered LDS, counted vmcnt.
// Stage 2 K-steps ahead via global_load_lds (frag-major, zero conflicts);
// s_waitcnt vmcnt(4) + raw s_barrier per step (drain only at the last step).
// Fused epilogue: exp + colsum atomics + diagonal sx extraction.
__global__ __launch_bounds__(256) void kC(const ushort_t* __restrict__ xbf,
    const ushort_t* __restrict__ sums_bf, const float* __restrict__ rcn,
    const float* __restrict__ rxn, float* __restrict__ colsum,
    float* __restrict__ sdiag_dot, const float* __restrict__ bp) {
  __shared__ ushort_t lds[3][8192];   // 3 x 16KB: [A frags 0..7 | B frags 0..7]
  const int b = blockIdx.x;
  const int xcd = b & 7;
  const int inner = b >> 3;
  const int nt = inner & 3;                      // 4 n-blocks of a j-tile on same XCD
  const int jt = xcd + ((inner >> 2) << 3);
  const int n0 = nt * 128, j0 = jt * 128;
  const int t = threadIdx.x, wv = t >> 6, l = t & 63;
  const int wm = wv >> 1, wj = wv & 1;

// stage K-step KS_ into buffer BUF_: 4 gload_lds per thread (2 A + 2 B frags)
#define STAGE(KS_, BUF_) {                                                     \
    const int k0_ = (KS_) * 32;                                                \
    const ushort_t* As_ = sums_bf + (size_t)(n0 + (l & 15)) * 768 + k0_ + (l >> 4) * 8; \
    const ushort_t* Bs_ = xbf + (size_t)(j0 + (l & 15)) * 768 + k0_ + (l >> 4) * 8;     \
    __builtin_amdgcn_global_load_lds(GPTR(As_ + (size_t)(wv * 2) * (16 * 768)),         \
        LPTR(&lds[BUF_][(wv * 2) * 512]), 16, 0, 0);                           \
    __builtin_amdgcn_global_load_lds(GPTR(As_ + (size_t)(wv * 2 + 1) * (16 * 768)),     \
        LPTR(&lds[BUF_][(wv * 2 + 1) * 512]), 16, 0, 0);                       \
    __builtin_amdgcn_global_load_lds(GPTR(Bs_ + (size_t)(wv * 2) * (16 * 768)),         \
        LPTR(&lds[BUF_][4096 + (wv * 2) * 512]), 16, 0, 0);                    \
    __builtin_amdgcn_global_load_lds(GPTR(Bs_ + (size_t)(wv * 2 + 1) * (16 * 768)),     \
        LPTR(&lds[BUF_][4096 + (wv * 2 + 1) * 512]), 16, 0, 0);                \
  }

#define COMPUTE(BUF_) {                                                        \
    short8 af_[4], bf_[4];                                                     \
    _Pragma("unroll")                                                          \
    for (int mi = 0; mi < 4; ++mi)                                             \
      af_[mi] = *(const short8*)&lds[BUF_][(wm * 4 + mi) * 512 + l * 8];       \
    _Pragma("unroll")                                                          \
    for (int ni = 0; ni < 4; ++ni)                                             \
      bf_[ni] = *(const short8*)&lds[BUF_][4096 + (wj * 4 + ni) * 512 + l * 8];\
    _Pragma("unroll")                                                          \
    for (int mi = 0; mi < 4; ++mi)                                             \
      _Pragma("unroll")                                                        \
      for (int ni = 0; ni < 4; ++ni)                                           \
        acc[mi][ni] = __builtin_amdgcn_mfma_f32_16x16x32_bf16(                 \
            af_[mi], bf_[ni], acc[mi][ni], 0, 0, 0);                           \
  }

// one pipelined step: wait S_KS landed (keep S_{KS+1} in flight), barrier,
// issue S_{KS+2} into the buffer compute(KS-1) just vacated, compute S_KS.
#define ITER(KS_, CB_, SB_) {                                                  \
    if ((KS_) < 23) { asm volatile("s_waitcnt vmcnt(4)" ::: "memory"); }       \
    else            { asm volatile("s_waitcnt vmcnt(0)" ::: "memory"); }       \
    __builtin_amdgcn_s_barrier();                                              \
    __builtin_amdgcn_sched_barrier(0);                                         \
    if ((KS_) + 2 < 24) STAGE((KS_) + 2, SB_)                                  \
    COMPUTE(CB_)                                                               \
  }

  floatx4 acc[4][4];
#pragma unroll
  for (int mi = 0; mi < 4; ++mi)
#pragma unroll
    for (int ni = 0; ni < 4; ++ni) acc[mi][ni] = (floatx4){0.f, 0.f, 0.f, 0.f};

  STAGE(0, 0)
  STAGE(1, 1)

  for (int kb = 0; kb < 24; kb += 3) {
    ITER(kb + 0, 0, 2)
    ITER(kb + 1, 1, 0)
    ITER(kb + 2, 2, 1)
  }

  // ---- epilogue: S = acc * rcn[n] * rxn[j] + b ; colsum += exp(S); diag sx.
  const float bb = *bp;
  float rcv[16], rxv[4], p[4] = {0.f, 0.f, 0.f, 0.f};
#pragma unroll
  for (int mi = 0; mi < 4; ++mi) {
    float4 rr = *(const float4*)&rcn[n0 + wm * 64 + mi * 16 + ((l >> 4) << 2)];
    rcv[mi * 4 + 0] = rr.x; rcv[mi * 4 + 1] = rr.y;
    rcv[mi * 4 + 2] = rr.z; rcv[mi * 4 + 3] = rr.w;
  }
#pragma unroll
  for (int ni = 0; ni < 4; ++ni)
    rxv[ni] = rxn[j0 + wj * 64 + ni * 16 + (l & 15)];
  const bool diagblk = (nt == (jt >> 6));

#pragma unroll
  for (int mi = 0; mi < 4; ++mi)
#pragma unroll
    for (int ni = 0; ni < 4; ++ni) {
      floatx4 a = acc[mi][ni];
#pragma unroll
      for (int q = 0; q < 4; ++q)
        p[ni] += __expf(a[q] * rcv[mi * 4 + q] * rxv[ni] + bb);
      if (diagblk) {
        const int jg = j0 + wj * 64 + ni * 16 + (l & 15);
#pragma unroll
        for (int q = 0; q < 4; ++q) {
          const int mg = n0 + wm * 64 + mi * 16 + ((l >> 4) << 2) + q;
          if (mg == (jg >> 6)) sdiag_dot[jg] = a[q];
        }
      }
    }
#pragma unroll
  for (int ni = 0; ni < 4; ++ni) {
    p[ni] += __shfl_xor(p[ni], 16, 64);
    p[ni] += __shfl_xor(p[ni], 32, 64);
  }
  if (l < 16) {
#pragma unroll
    for (int ni = 0; ni < 4; ++ni)
      atomicAdd(&colsum[j0 + wj * 64 + ni * 16 + l], p[ni]);
  }
}

// ---- kD: per-sample loss from colsum + diagonal dot, reduce to scalar -----
__global__ __launch_bounds__(256) void kD(const float* __restrict__ colsum,
    const float* __restrict__ sdiag_dot, const float* __restrict__ xx,
    const float* __restrict__ ss, const float* __restrict__ rcn,
    const float* __restrict__ wp, const float* __restrict__ bp,
    float* __restrict__ out) {
  const int j = blockIdx.x * 256 + threadIdx.x;
  const int i = j >> 6;
  const float ww = *wp, bb = *bp;
  const float sx = sdiag_dot[j];
  const float xxv = xx[j];
  const float xn = fmaxf(sqrtf(xxv), EPS);
  const float rx = 1.0f / xn;
  const float sd = sx * rcn[i] * rx + bb;                         // S_diag
  const float exn = sqrtf(fmaxf(ss[i] - 2.f * sx + xxv, 0.f)) * (1.f / 63.f);
  const float edot = (sx - xxv) * (1.f / 63.f);
  const float sm = ww * edot / (fmaxf(exn, EPS) * xn) + bb;       // S_same
  const float tot = colsum[j] - __expf(sd) + __expf(sm);
  float L = -sm + logf(fmaxf(tot, 1e-30f));
  for (int o = 32; o; o >>= 1) L += __shfl_xor(L, o, 64);
  __shared__ float red[4];
  if ((threadIdx.x & 63) == 0) red[threadIdx.x >> 6] = L;
  __syncthreads();
  if (threadIdx.x == 0) atomicAdd(out, red[0] + red[1] + red[2] + red[3]);
}

extern "C" void kernel_launch(void* const* d_in, const int* in_sizes, int n_in,
                              void* d_out, int out_size, void* d_ws, size_t ws_size,
                              hipStream_t stream) {
  const float* x  = (const float*)d_in[0];
  const float* wp = (const float*)d_in[1];
  const float* bp = (const float*)d_in[2];
  float* out = (float*)d_out;

  // ws layout (float offsets):
  float* fws = (float*)d_ws;
  float* ss        = fws;             // 512
  float* rcn       = fws + 512;       // 512
  float* xx        = fws + 1024;      // 32768
  float* rxn       = fws + 33792;     // 32768
  float* colsum    = fws + 66560;     // 32768
  float* sdiag_dot = fws + 99328;     // 32768
  ushort_t* sums_bf = (ushort_t*)(fws + 132096);   // 393216 ushorts
  ushort_t* xbf     = (ushort_t*)(fws + 328704);   // 25165824 ushorts
  // total = 12911616 floats ~= 49.3 MiB

  hipMemsetAsync(colsum, 0, 32768 * sizeof(float), stream);
  hipMemsetAsync(out, 0, sizeof(float), stream);

  kA<<<512, 256, 0, stream>>>(x, xbf, sums_bf, ss, rcn, xx, rxn, wp);
  kC<<<1024, 256, 0, stream>>>(xbf, sums_bf, rcn, rxn, colsum, sdiag_dot, bp);
  kD<<<128, 256, 0, stream>>>(colsum, sdiag_dot, xx, ss, rcn, wp, bp, out);
}

// Round 9
// 78.160 us; speedup vs baseline: 3.8144x; 1.1129x over previous
//
#include <hip/hip_runtime.h>
#include <hip/hip_bf16.h>
#include <math.h>

#define EPS 1e-8f

typedef __attribute__((ext_vector_type(8))) short short8;
typedef __attribute__((ext_vector_type(4))) float floatx4;
typedef unsigned short ushort_t;

#define GPTR(p) ((const __attribute__((address_space(1))) void*)(p))
#define LPTR(p) ((__attribute__((address_space(3))) void*)(p))

__device__ __forceinline__ unsigned short f2bf(float f) {
  unsigned int u = __float_as_uint(f);
  u += 0x7FFFu + ((u >> 16) & 1u);   // RNE
  return (unsigned short)(u >> 16);
}
__device__ __forceinline__ unsigned int pack2bf(float a, float b) {
  return (unsigned int)f2bf(a) | ((unsigned int)f2bf(b) << 16);
}

// ---- kA: one speaker per block. x -> x_bf, row norms (xx, rxn),
//          column sums -> sums_bf, ss, rcn. Single 96MB pass over x.
__global__ __launch_bounds__(256) void kA(const float* __restrict__ x,
    ushort_t* __restrict__ xbf, ushort_t* __restrict__ sums_bf,
    float* __restrict__ ss, float* __restrict__ rcn,
    float* __restrict__ xx, float* __restrict__ rxn,
    const float* __restrict__ wp) {
  const int n = blockIdx.x;
  const int t = threadIdx.x;
  const int wv = t >> 6, l = t & 63;
  __shared__ float csum[4][768];   // 12 KB
  float4 cs0 = {0,0,0,0}, cs1 = {0,0,0,0}, cs2 = {0,0,0,0};

  for (int r = 0; r < 16; ++r) {
    const int row = wv * 16 + r;
    const size_t base = ((size_t)n * 64 + row) * 768;
    const float* rp = x + base;
    float4 v0 = *(const float4*)(rp + l * 4);
    float4 v1 = *(const float4*)(rp + l * 4 + 256);
    float4 v2 = *(const float4*)(rp + l * 4 + 512);
    uint2 b0 = { pack2bf(v0.x, v0.y), pack2bf(v0.z, v0.w) };
    uint2 b1 = { pack2bf(v1.x, v1.y), pack2bf(v1.z, v1.w) };
    uint2 b2 = { pack2bf(v2.x, v2.y), pack2bf(v2.z, v2.w) };
    *(uint2*)(xbf + base + l * 4)       = b0;
    *(uint2*)(xbf + base + l * 4 + 256) = b1;
    *(uint2*)(xbf + base + l * 4 + 512) = b2;
    float rq = v0.x*v0.x + v0.y*v0.y + v0.z*v0.z + v0.w*v0.w
             + v1.x*v1.x + v1.y*v1.y + v1.z*v1.z + v1.w*v1.w
             + v2.x*v2.x + v2.y*v2.y + v2.z*v2.z + v2.w*v2.w;
    for (int o = 32; o; o >>= 1) rq += __shfl_xor(rq, o, 64);
    if (l == 0) {
      const int j = n * 64 + row;
      xx[j] = rq;
      rxn[j] = 1.0f / fmaxf(sqrtf(rq), EPS);
    }
    cs0.x += v0.x; cs0.y += v0.y; cs0.z += v0.z; cs0.w += v0.w;
    cs1.x += v1.x; cs1.y += v1.y; cs1.z += v1.z; cs1.w += v1.w;
    cs2.x += v2.x; cs2.y += v2.y; cs2.z += v2.z; cs2.w += v2.w;
  }
  *(float4*)&csum[wv][l * 4]       = cs0;
  *(float4*)&csum[wv][l * 4 + 256] = cs1;
  *(float4*)&csum[wv][l * 4 + 512] = cs2;
  __syncthreads();

  float lss = 0.f;
#pragma unroll
  for (int q = 0; q < 3; ++q) {
    const int c = t + q * 256;
    const float s = csum[0][c] + csum[1][c] + csum[2][c] + csum[3][c];
    sums_bf[(size_t)n * 768 + c] = f2bf(s);
    lss += s * s;
  }
  for (int o = 32; o; o >>= 1) lss += __shfl_xor(lss, o, 64);
  __syncthreads();
  if (l == 0) csum[1][wv] = lss;   // reuse LDS slot
  __syncthreads();
  if (t == 0) {
    const float v = csum[1][0] + csum[1][1] + csum[1][2] + csum[1][3];
    ss[n] = v;
    rcn[n] = (*wp) / fmaxf(sqrtf(v), 64.f * EPS);   // w / (M * cn)
  }
}

// ---- kC: MFMA GEMM, tile 128n x 256j, 512 blocks x 8 waves (512 thr).
// Triple-buffered LDS (3 x 24KB), counted vmcnt(3), 1 barrier/step.
// Frag-major LDS via global_load_lds (zero bank conflicts).
// All 512 blocks co-resident (2/CU): zero tail rounds.
__global__ __launch_bounds__(512, 4) void kC(const ushort_t* __restrict__ xbf,
    const ushort_t* __restrict__ sums_bf, const float* __restrict__ rcn,
    const float* __restrict__ rxn, float* __restrict__ colsum,
    float* __restrict__ sdiag_dot, const float* __restrict__ bp) {
  __shared__ ushort_t lds[3][12288];   // 3 x 24KB: [A frags 0..7 | B frags 0..15]
  const int b = blockIdx.x;
  const int xcd = b & 7;
  const int inner = b >> 3;
  const int nt = inner & 3;                    // 4 n-blocks of a j-tile on same XCD
  const int jt = xcd + ((inner >> 2) << 3);    // 0..127
  const int n0 = nt * 128, j0 = jt * 256;
  const int t = threadIdx.x, wv = t >> 6, l = t & 63;
  const int wm = wv >> 2, wj = wv & 3;         // 2(m) x 4(j) wave grid, 64x64 each

// stage K-step KS_ into buffer BUF_: 3 gload_lds per thread (1 A + 2 B frags)
#define STAGE(KS_, BUF_) {                                                     \
    const int k0_ = (KS_) * 32;                                                \
    const ushort_t* As_ = sums_bf + (size_t)(n0 + wv * 16 + (l & 15)) * 768 +  \
                          k0_ + (l >> 4) * 8;                                  \
    const ushort_t* Bs_ = xbf + (size_t)(j0 + (l & 15)) * 768 +                \
                          k0_ + (l >> 4) * 8;                                  \
    __builtin_amdgcn_global_load_lds(GPTR(As_),                                \
        LPTR(&lds[BUF_][wv * 512]), 16, 0, 0);                                 \
    __builtin_amdgcn_global_load_lds(GPTR(Bs_ + (size_t)(wv * 2) * (16 * 768)),\
        LPTR(&lds[BUF_][4096 + (wv * 2) * 512]), 16, 0, 0);                    \
    __builtin_amdgcn_global_load_lds(GPTR(Bs_ + (size_t)(wv * 2 + 1) * (16 * 768)), \
        LPTR(&lds[BUF_][4096 + (wv * 2 + 1) * 512]), 16, 0, 0);                \
  }

#define COMPUTE(BUF_) {                                                        \
    short8 af_[4], bf_[4];                                                     \
    _Pragma("unroll")                                                          \
    for (int mi = 0; mi < 4; ++mi)                                             \
      af_[mi] = *(const short8*)&lds[BUF_][(wm * 4 + mi) * 512 + l * 8];       \
    _Pragma("unroll")                                                          \
    for (int ni = 0; ni < 4; ++ni)                                             \
      bf_[ni] = *(const short8*)&lds[BUF_][4096 + (wj * 4 + ni) * 512 + l * 8];\
    _Pragma("unroll")                                                          \
    for (int mi = 0; mi < 4; ++mi)                                             \
      _Pragma("unroll")                                                        \
      for (int ni = 0; ni < 4; ++ni)                                           \
        acc[mi][ni] = __builtin_amdgcn_mfma_f32_16x16x32_bf16(                 \
            af_[mi], bf_[ni], acc[mi][ni], 0, 0, 0);                           \
  }

// wait stage KS_ landed (keep newest stage in flight), barrier,
// stage KS_+2 into the buffer compute(KS_-1) vacated, compute KS_.
#define ITER(KS_, CB_, SB_) {                                                  \
    if ((KS_) < 23) { asm volatile("s_waitcnt vmcnt(3)" ::: "memory"); }       \
    else            { asm volatile("s_waitcnt vmcnt(0)" ::: "memory"); }       \
    __builtin_amdgcn_s_barrier();                                              \
    __builtin_amdgcn_sched_barrier(0);                                         \
    if ((KS_) + 2 < 24) STAGE((KS_) + 2, SB_)                                  \
    COMPUTE(CB_)                                                               \
  }

  floatx4 acc[4][4];
#pragma unroll
  for (int mi = 0; mi < 4; ++mi)
#pragma unroll
    for (int ni = 0; ni < 4; ++ni) acc[mi][ni] = (floatx4){0.f, 0.f, 0.f, 0.f};

  STAGE(0, 0)
  STAGE(1, 1)

  for (int kb = 0; kb < 24; kb += 3) {
    ITER(kb + 0, 0, 2)
    ITER(kb + 1, 1, 0)
    ITER(kb + 2, 2, 1)
  }

  // ---- epilogue: S = acc * rcn[n] * rxn[j] + b ; colsum += exp(S); diag sx.
  const float bb = *bp;
  float rcv[16], rxv[4], p[4] = {0.f, 0.f, 0.f, 0.f};
#pragma unroll
  for (int mi = 0; mi < 4; ++mi) {
    float4 rr = *(const float4*)&rcn[n0 + wm * 64 + mi * 16 + ((l >> 4) << 2)];
    rcv[mi * 4 + 0] = rr.x; rcv[mi * 4 + 1] = rr.y;
    rcv[mi * 4 + 2] = rr.z; rcv[mi * 4 + 3] = rr.w;
  }
#pragma unroll
  for (int ni = 0; ni < 4; ++ni)
    rxv[ni] = rxn[j0 + wj * 64 + ni * 16 + (l & 15)];
  const bool diagblk = (nt == (jt >> 5));   // n-tile holding speakers jt*4..jt*4+3

#pragma unroll
  for (int mi = 0; mi < 4; ++mi)
#pragma unroll
    for (int ni = 0; ni < 4; ++ni) {
      floatx4 a = acc[mi][ni];
#pragma unroll
      for (int q = 0; q < 4; ++q)
        p[ni] += __expf(a[q] * rcv[mi * 4 + q] * rxv[ni] + bb);
      if (diagblk) {
        const int jg = j0 + wj * 64 + ni * 16 + (l & 15);
#pragma unroll
        for (int q = 0; q < 4; ++q) {
          const int mg = n0 + wm * 64 + mi * 16 + ((l >> 4) << 2) + q;
          if (mg == (jg >> 6)) sdiag_dot[jg] = a[q];
        }
      }
    }
#pragma unroll
  for (int ni = 0; ni < 4; ++ni) {
    p[ni] += __shfl_xor(p[ni], 16, 64);
    p[ni] += __shfl_xor(p[ni], 32, 64);
  }
  if (l < 16) {
#pragma unroll
    for (int ni = 0; ni < 4; ++ni)
      atomicAdd(&colsum[j0 + wj * 64 + ni * 16 + l], p[ni]);
  }
}

// ---- kD: per-sample loss from colsum + diagonal dot, reduce to scalar -----
__global__ __launch_bounds__(256) void kD(const float* __restrict__ colsum,
    const float* __restrict__ sdiag_dot, const float* __restrict__ xx,
    const float* __restrict__ ss, const float* __restrict__ rcn,
    const float* __restrict__ wp, const float* __restrict__ bp,
    float* __restrict__ out) {
  const int j = blockIdx.x * 256 + threadIdx.x;
  const int i = j >> 6;
  const float ww = *wp, bb = *bp;
  const float sx = sdiag_dot[j];
  const float xxv = xx[j];
  const float xn = fmaxf(sqrtf(xxv), EPS);
  const float rx = 1.0f / xn;
  const float sd = sx * rcn[i] * rx + bb;                         // S_diag
  const float exn = sqrtf(fmaxf(ss[i] - 2.f * sx + xxv, 0.f)) * (1.f / 63.f);
  const float edot = (sx - xxv) * (1.f / 63.f);
  const float sm = ww * edot / (fmaxf(exn, EPS) * xn) + bb;       // S_same
  const float tot = colsum[j] - __expf(sd) + __expf(sm);
  float L = -sm + logf(fmaxf(tot, 1e-30f));
  for (int o = 32; o; o >>= 1) L += __shfl_xor(L, o, 64);
  __shared__ float red[4];
  if ((threadIdx.x & 63) == 0) red[threadIdx.x >> 6] = L;
  __syncthreads();
  if (threadIdx.x == 0) atomicAdd(out, red[0] + red[1] + red[2] + red[3]);
}

extern "C" void kernel_launch(void* const* d_in, const int* in_sizes, int n_in,
                              void* d_out, int out_size, void* d_ws, size_t ws_size,
                              hipStream_t stream) {
  const float* x  = (const float*)d_in[0];
  const float* wp = (const float*)d_in[1];
  const float* bp = (const float*)d_in[2];
  float* out = (float*)d_out;

  // ws layout (float offsets):
  float* fws = (float*)d_ws;
  float* ss        = fws;             // 512
  float* rcn       = fws + 512;       // 512
  float* xx        = fws + 1024;      // 32768
  float* rxn       = fws + 33792;     // 32768
  float* colsum    = fws + 66560;     // 32768
  float* sdiag_dot = fws + 99328;     // 32768
  ushort_t* sums_bf = (ushort_t*)(fws + 132096);   // 393216 ushorts
  ushort_t* xbf     = (ushort_t*)(fws + 328704);   // 25165824 ushorts
  // total = 12911616 floats ~= 49.3 MiB

  hipMemsetAsync(colsum, 0, 32768 * sizeof(float), stream);
  hipMemsetAsync(out, 0, sizeof(float), stream);

  kA<<<512, 256, 0, stream>>>(x, xbf, sums_bf, ss, rcn, xx, rxn, wp);
  kC<<<512, 512, 0, stream>>>(xbf, sums_bf, rcn, rxn, colsum, sdiag_dot, bp);
  kD<<<128, 256, 0, stream>>>(colsum, sdiag_dot, xx, ss, rcn, wp, bp, out);
}

// Round 10
// 71.130 us; speedup vs baseline: 4.1914x; 1.0988x over previous
//
#include <hip/hip_runtime.h>
#include <hip/hip_bf16.h>
#include <math.h>

#define EPS 1e-8f

typedef __attribute__((ext_vector_type(8))) short short8;
typedef __attribute__((ext_vector_type(4))) float floatx4;
typedef unsigned short ushort_t;

#define GPTR(p) ((const __attribute__((address_space(1))) void*)(p))
#define LPTR(p) ((__attribute__((address_space(3))) void*)(p))

__device__ __forceinline__ unsigned short f2bf(float f) {
  unsigned int u = __float_as_uint(f);
  u += 0x7FFFu + ((u >> 16) & 1u);   // RNE
  return (unsigned short)(u >> 16);
}
__device__ __forceinline__ unsigned int pack2bf(float a, float b) {
  return (unsigned int)f2bf(a) | ((unsigned int)f2bf(b) << 16);
}

// ---- kA: one speaker per block. x -> x_bf, row norms (xx, rxn),
//          column sums -> sums_bf, ss, rcn. Single 96MB pass over x.
__global__ __launch_bounds__(256) void kA(const float* __restrict__ x,
    ushort_t* __restrict__ xbf, ushort_t* __restrict__ sums_bf,
    float* __restrict__ ss, float* __restrict__ rcn,
    float* __restrict__ xx, float* __restrict__ rxn,
    const float* __restrict__ wp) {
  const int n = blockIdx.x;
  const int t = threadIdx.x;
  const int wv = t >> 6, l = t & 63;
  __shared__ float csum[4][768];   // 12 KB
  float4 cs0 = {0,0,0,0}, cs1 = {0,0,0,0}, cs2 = {0,0,0,0};

  for (int r = 0; r < 16; ++r) {
    const int row = wv * 16 + r;
    const size_t base = ((size_t)n * 64 + row) * 768;
    const float* rp = x + base;
    float4 v0 = *(const float4*)(rp + l * 4);
    float4 v1 = *(const float4*)(rp + l * 4 + 256);
    float4 v2 = *(const float4*)(rp + l * 4 + 512);
    uint2 b0 = { pack2bf(v0.x, v0.y), pack2bf(v0.z, v0.w) };
    uint2 b1 = { pack2bf(v1.x, v1.y), pack2bf(v1.z, v1.w) };
    uint2 b2 = { pack2bf(v2.x, v2.y), pack2bf(v2.z, v2.w) };
    *(uint2*)(xbf + base + l * 4)       = b0;
    *(uint2*)(xbf + base + l * 4 + 256) = b1;
    *(uint2*)(xbf + base + l * 4 + 512) = b2;
    float rq = v0.x*v0.x + v0.y*v0.y + v0.z*v0.z + v0.w*v0.w
             + v1.x*v1.x + v1.y*v1.y + v1.z*v1.z + v1.w*v1.w
             + v2.x*v2.x + v2.y*v2.y + v2.z*v2.z + v2.w*v2.w;
    for (int o = 32; o; o >>= 1) rq += __shfl_xor(rq, o, 64);
    if (l == 0) {
      const int j = n * 64 + row;
      xx[j] = rq;
      rxn[j] = 1.0f / fmaxf(sqrtf(rq), EPS);
    }
    cs0.x += v0.x; cs0.y += v0.y; cs0.z += v0.z; cs0.w += v0.w;
    cs1.x += v1.x; cs1.y += v1.y; cs1.z += v1.z; cs1.w += v1.w;
    cs2.x += v2.x; cs2.y += v2.y; cs2.z += v2.z; cs2.w += v2.w;
  }
  *(float4*)&csum[wv][l * 4]       = cs0;
  *(float4*)&csum[wv][l * 4 + 256] = cs1;
  *(float4*)&csum[wv][l * 4 + 512] = cs2;
  __syncthreads();

  float lss = 0.f;
#pragma unroll
  for (int q = 0; q < 3; ++q) {
    const int c = t + q * 256;
    const float s = csum[0][c] + csum[1][c] + csum[2][c] + csum[3][c];
    sums_bf[(size_t)n * 768 + c] = f2bf(s);
    lss += s * s;
  }
  for (int o = 32; o; o >>= 1) lss += __shfl_xor(lss, o, 64);
  __syncthreads();
  if (l == 0) csum[1][wv] = lss;   // reuse LDS slot
  __syncthreads();
  if (t == 0) {
    const float v = csum[1][0] + csum[1][1] + csum[1][2] + csum[1][3];
    ss[n] = v;
    rcn[n] = (*wp) / fmaxf(sqrtf(v), 64.f * EPS);   // w / (M * cn)
  }
}

// ---- kC v3: 256n x 256j tile, 256 blocks (1/CU), 8 waves of 128n x 64j
// (mi=8, ni=4 -> 12 ds_read / 32 MFMA = 0.375 reads/MFMA).
// 4 LDS buffers x 32KB, stage 2 steps ahead, counted vmcnt(4), 2-phase
// steps with setprio-wrapped MFMA clusters (8-phase-template style).
__global__ __launch_bounds__(512, 2) void kC(const ushort_t* __restrict__ xbf,
    const ushort_t* __restrict__ sums_bf, const float* __restrict__ rcn,
    const float* __restrict__ rxn, float* __restrict__ colsum,
    float* __restrict__ sdiag_dot, const float* __restrict__ bp) {
  __shared__ ushort_t lds[4][16384];   // 4 x 32KB: [A frags 0..15 | B frags 0..15]
  const int b = blockIdx.x;
  const int xcd = b & 7;
  const int inner = b >> 3;            // 0..31
  const int nt = inner & 1;            // n-tile twins of a j-tile share an XCD
  const int jt = xcd + ((inner >> 1) << 3);   // 0..127
  const int n0 = nt * 256, j0 = jt * 256;
  const int t = threadIdx.x, wv = t >> 6, l = t & 63;
  const int wm = wv >> 2, wj = wv & 3; // 2(m) x 4(j) wave grid; wave = 128n x 64j

// stage K-step KS_: A half (2 gload_lds/thread), B half (2 gload_lds/thread)
#define STAGE_A(KS_, BUF_) {                                                   \
    const int k0_ = (KS_) * 32;                                                \
    const ushort_t* As_ = sums_bf + (size_t)(n0 + wv * 16 + (l & 15)) * 768 +  \
                          k0_ + (l >> 4) * 8;                                  \
    __builtin_amdgcn_global_load_lds(GPTR(As_),                                \
        LPTR(&lds[BUF_][wv * 512]), 16, 0, 0);                                 \
    __builtin_amdgcn_global_load_lds(GPTR(As_ + (size_t)128 * 768),            \
        LPTR(&lds[BUF_][(wv + 8) * 512]), 16, 0, 0);                           \
  }
#define STAGE_B(KS_, BUF_) {                                                   \
    const int k0_ = (KS_) * 32;                                                \
    const ushort_t* Bs_ = xbf + (size_t)(j0 + wv * 16 + (l & 15)) * 768 +      \
                          k0_ + (l >> 4) * 8;                                  \
    __builtin_amdgcn_global_load_lds(GPTR(Bs_),                                \
        LPTR(&lds[BUF_][8192 + wv * 512]), 16, 0, 0);                          \
    __builtin_amdgcn_global_load_lds(GPTR(Bs_ + (size_t)128 * 768),            \
        LPTR(&lds[BUF_][8192 + (wv + 8) * 512]), 16, 0, 0);                    \
  }

  floatx4 acc[8][4];
#pragma unroll
  for (int mi = 0; mi < 8; ++mi)
#pragma unroll
    for (int ni = 0; ni < 4; ++ni) acc[mi][ni] = (floatx4){0.f, 0.f, 0.f, 0.f};

  STAGE_A(0, 0) STAGE_B(0, 0)
  STAGE_A(1, 1) STAGE_B(1, 1)          // 8 loads/thread outstanding

  for (int kb = 0; kb < 24; ++kb) {
    if (kb < 23) { asm volatile("s_waitcnt vmcnt(4)" ::: "memory"); }
    else         { asm volatile("s_waitcnt vmcnt(0)" ::: "memory"); }
    __builtin_amdgcn_s_barrier();
    __builtin_amdgcn_sched_barrier(0);
    const int cb = kb & 3, sb = (kb + 2) & 3;

    // ---- phase 0: af[0..3] + bf[0..3] reads, stage-A, 16 MFMA (mi 0..3)
    short8 af[4], bf[4];
#pragma unroll
    for (int mi = 0; mi < 4; ++mi)
      af[mi] = *(const short8*)&lds[cb][(wm * 8 + mi) * 512 + l * 8];
#pragma unroll
    for (int ni = 0; ni < 4; ++ni)
      bf[ni] = *(const short8*)&lds[cb][8192 + (wj * 4 + ni) * 512 + l * 8];
    if (kb < 22) STAGE_A(kb + 2, sb)
    asm volatile("s_waitcnt lgkmcnt(0)" ::: "memory");
    __builtin_amdgcn_sched_barrier(0);
    __builtin_amdgcn_s_setprio(1);
#pragma unroll
    for (int mi = 0; mi < 4; ++mi)
#pragma unroll
      for (int ni = 0; ni < 4; ++ni)
        acc[mi][ni] = __builtin_amdgcn_mfma_f32_16x16x32_bf16(
            af[mi], bf[ni], acc[mi][ni], 0, 0, 0);
    __builtin_amdgcn_s_setprio(0);
    __builtin_amdgcn_s_barrier();

    // ---- phase 1: af[4..7] reads, stage-B, 16 MFMA (mi 4..7)
    short8 ag[4];
#pragma unroll
    for (int mi = 0; mi < 4; ++mi)
      ag[mi] = *(const short8*)&lds[cb][(wm * 8 + 4 + mi) * 512 + l * 8];
    if (kb < 22) STAGE_B(kb + 2, sb)
    asm volatile("s_waitcnt lgkmcnt(0)" ::: "memory");
    __builtin_amdgcn_sched_barrier(0);
    __builtin_amdgcn_s_setprio(1);
#pragma unroll
    for (int mi = 0; mi < 4; ++mi)
#pragma unroll
      for (int ni = 0; ni < 4; ++ni)
        acc[mi + 4][ni] = __builtin_amdgcn_mfma_f32_16x16x32_bf16(
            ag[mi], bf[ni], acc[mi + 4][ni], 0, 0, 0);
    __builtin_amdgcn_s_setprio(0);
  }

  // ---- epilogue: S = acc * rcn[n] * rxn[j] + b ; colsum += exp(S); diag sx.
  const float bb = *bp;
  float rxv[4], p[4] = {0.f, 0.f, 0.f, 0.f};
#pragma unroll
  for (int ni = 0; ni < 4; ++ni)
    rxv[ni] = rxn[j0 + wj * 64 + ni * 16 + (l & 15)];
  const bool diagblk = (nt == (jt >> 6));

#pragma unroll
  for (int mi = 0; mi < 8; ++mi) {
    float4 rr = *(const float4*)&rcn[n0 + wm * 128 + mi * 16 + ((l >> 4) << 2)];
    const float rc[4] = {rr.x, rr.y, rr.z, rr.w};
#pragma unroll
    for (int ni = 0; ni < 4; ++ni) {
      floatx4 a = acc[mi][ni];
#pragma unroll
      for (int q = 0; q < 4; ++q)
        p[ni] += __expf(a[q] * rc[q] * rxv[ni] + bb);
      if (diagblk) {
        const int jg = j0 + wj * 64 + ni * 16 + (l & 15);
#pragma unroll
        for (int q = 0; q < 4; ++q) {
          const int mg = n0 + wm * 128 + mi * 16 + ((l >> 4) << 2) + q;
          if (mg == (jg >> 6)) sdiag_dot[jg] = a[q];
        }
      }
    }
  }
#pragma unroll
  for (int ni = 0; ni < 4; ++ni) {
    p[ni] += __shfl_xor(p[ni], 16, 64);
    p[ni] += __shfl_xor(p[ni], 32, 64);
  }
  if (l < 16) {
#pragma unroll
    for (int ni = 0; ni < 4; ++ni)
      atomicAdd(&colsum[j0 + wj * 64 + ni * 16 + l], p[ni]);
  }
}

// ---- kD: per-sample loss from colsum + diagonal dot, reduce to scalar -----
__global__ __launch_bounds__(256) void kD(const float* __restrict__ colsum,
    const float* __restrict__ sdiag_dot, const float* __restrict__ xx,
    const float* __restrict__ ss, const float* __restrict__ rcn,
    const float* __restrict__ wp, const float* __restrict__ bp,
    float* __restrict__ out) {
  const int j = blockIdx.x * 256 + threadIdx.x;
  const int i = j >> 6;
  const float ww = *wp, bb = *bp;
  const float sx = sdiag_dot[j];
  const float xxv = xx[j];
  const float xn = fmaxf(sqrtf(xxv), EPS);
  const float rx = 1.0f / xn;
  const float sd = sx * rcn[i] * rx + bb;                         // S_diag
  const float exn = sqrtf(fmaxf(ss[i] - 2.f * sx + xxv, 0.f)) * (1.f / 63.f);
  const float edot = (sx - xxv) * (1.f / 63.f);
  const float sm = ww * edot / (fmaxf(exn, EPS) * xn) + bb;       // S_same
  const float tot = colsum[j] - __expf(sd) + __expf(sm);
  float L = -sm + logf(fmaxf(tot, 1e-30f));
  for (int o = 32; o; o >>= 1) L += __shfl_xor(L, o, 64);
  __shared__ float red[4];
  if ((threadIdx.x & 63) == 0) red[threadIdx.x >> 6] = L;
  __syncthreads();
  if (threadIdx.x == 0) atomicAdd(out, red[0] + red[1] + red[2] + red[3]);
}

extern "C" void kernel_launch(void* const* d_in, const int* in_sizes, int n_in,
                              void* d_out, int out_size, void* d_ws, size_t ws_size,
                              hipStream_t stream) {
  const float* x  = (const float*)d_in[0];
  const float* wp = (const float*)d_in[1];
  const float* bp = (const float*)d_in[2];
  float* out = (float*)d_out;

  // ws layout (float offsets):
  float* fws = (float*)d_ws;
  float* ss        = fws;             // 512
  float* rcn       = fws + 512;       // 512
  float* xx        = fws + 1024;      // 32768
  float* rxn       = fws + 33792;     // 32768
  float* colsum    = fws + 66560;     // 32768
  float* sdiag_dot = fws + 99328;     // 32768
  ushort_t* sums_bf = (ushort_t*)(fws + 132096);   // 393216 ushorts
  ushort_t* xbf     = (ushort_t*)(fws + 328704);   // 25165824 ushorts
  // total = 12911616 floats ~= 49.3 MiB

  hipMemsetAsync(colsum, 0, 32768 * sizeof(float), stream);
  hipMemsetAsync(out, 0, sizeof(float), stream);

  kA<<<512, 256, 0, stream>>>(x, xbf, sums_bf, ss, rcn, xx, rxn, wp);
  kC<<<256, 512, 0, stream>>>(xbf, sums_bf, rcn, rxn, colsum, sdiag_dot, bp);
  kD<<<128, 256, 0, stream>>>(colsum, sdiag_dot, xx, ss, rcn, wp, bp, out);
}

// Round 11
// 70.269 us; speedup vs baseline: 4.2428x; 1.0123x over previous
//
#include <hip/hip_runtime.h>
#include <hip/hip_bf16.h>
#include <math.h>

#define EPS 1e-8f

typedef __attribute__((ext_vector_type(8))) short short8;
typedef __attribute__((ext_vector_type(4))) float floatx4;
typedef unsigned short ushort_t;

#define GPTR(p) ((const __attribute__((address_space(1))) void*)(p))
#define LPTR(p) ((__attribute__((address_space(3))) void*)(p))

__device__ __forceinline__ unsigned short f2bf(float f) {
  unsigned int u = __float_as_uint(f);
  u += 0x7FFFu + ((u >> 16) & 1u);   // RNE
  return (unsigned short)(u >> 16);
}
__device__ __forceinline__ unsigned int pack2bf(float a, float b) {
  return (unsigned int)f2bf(a) | ((unsigned int)f2bf(b) << 16);
}

// ---- kA: one speaker per block. x -> x_bf, row norms (xx, rxn),
//          column sums -> sums_bf, ss, rcn. Single 96MB pass over x.
__global__ __launch_bounds__(256) void kA(const float* __restrict__ x,
    ushort_t* __restrict__ xbf, ushort_t* __restrict__ sums_bf,
    float* __restrict__ ss, float* __restrict__ rcn,
    float* __restrict__ xx, float* __restrict__ rxn,
    const float* __restrict__ wp) {
  const int n = blockIdx.x;
  const int t = threadIdx.x;
  const int wv = t >> 6, l = t & 63;
  __shared__ float csum[4][768];   // 12 KB
  float4 cs0 = {0,0,0,0}, cs1 = {0,0,0,0}, cs2 = {0,0,0,0};

  for (int r = 0; r < 16; ++r) {
    const int row = wv * 16 + r;
    const size_t base = ((size_t)n * 64 + row) * 768;
    const float* rp = x + base;
    float4 v0 = *(const float4*)(rp + l * 4);
    float4 v1 = *(const float4*)(rp + l * 4 + 256);
    float4 v2 = *(const float4*)(rp + l * 4 + 512);
    uint2 b0 = { pack2bf(v0.x, v0.y), pack2bf(v0.z, v0.w) };
    uint2 b1 = { pack2bf(v1.x, v1.y), pack2bf(v1.z, v1.w) };
    uint2 b2 = { pack2bf(v2.x, v2.y), pack2bf(v2.z, v2.w) };
    *(uint2*)(xbf + base + l * 4)       = b0;
    *(uint2*)(xbf + base + l * 4 + 256) = b1;
    *(uint2*)(xbf + base + l * 4 + 512) = b2;
    float rq = v0.x*v0.x + v0.y*v0.y + v0.z*v0.z + v0.w*v0.w
             + v1.x*v1.x + v1.y*v1.y + v1.z*v1.z + v1.w*v1.w
             + v2.x*v2.x + v2.y*v2.y + v2.z*v2.z + v2.w*v2.w;
    for (int o = 32; o; o >>= 1) rq += __shfl_xor(rq, o, 64);
    if (l == 0) {
      const int j = n * 64 + row;
      xx[j] = rq;
      rxn[j] = 1.0f / fmaxf(sqrtf(rq), EPS);
    }
    cs0.x += v0.x; cs0.y += v0.y; cs0.z += v0.z; cs0.w += v0.w;
    cs1.x += v1.x; cs1.y += v1.y; cs1.z += v1.z; cs1.w += v1.w;
    cs2.x += v2.x; cs2.y += v2.y; cs2.z += v2.z; cs2.w += v2.w;
  }
  *(float4*)&csum[wv][l * 4]       = cs0;
  *(float4*)&csum[wv][l * 4 + 256] = cs1;
  *(float4*)&csum[wv][l * 4 + 512] = cs2;
  __syncthreads();

  float lss = 0.f;
#pragma unroll
  for (int q = 0; q < 3; ++q) {
    const int c = t + q * 256;
    const float s = csum[0][c] + csum[1][c] + csum[2][c] + csum[3][c];
    sums_bf[(size_t)n * 768 + c] = f2bf(s);
    lss += s * s;
  }
  for (int o = 32; o; o >>= 1) lss += __shfl_xor(lss, o, 64);
  __syncthreads();
  if (l == 0) csum[1][wv] = lss;   // reuse LDS slot
  __syncthreads();
  if (t == 0) {
    const float v = csum[1][0] + csum[1][1] + csum[1][2] + csum[1][3];
    ss[n] = v;
    rcn[n] = (*wp) / fmaxf(sqrtf(v), 64.f * EPS);   // w / (M * cn)
  }
}

// ---- kC v4: 256n x 256j tile, 256 blocks (1/CU), 8 waves of 128n x 64j.
// SINGLE phase per K-step: 12 ds_reads + stage(kb+3) + lgkm(0) + 32 MFMA,
// ONE barrier per step, 3-deep prefetch across 4 LDS buffers, vmcnt(8).
__global__ __launch_bounds__(512, 2) void kC(const ushort_t* __restrict__ xbf,
    const ushort_t* __restrict__ sums_bf, const float* __restrict__ rcn,
    const float* __restrict__ rxn, float* __restrict__ colsum,
    float* __restrict__ sdiag_dot, const float* __restrict__ bp) {
  __shared__ ushort_t lds[4][16384];   // 4 x 32KB: [A frags 0..15 | B frags 0..15]
  const int b = blockIdx.x;
  const int xcd = b & 7;
  const int inner = b >> 3;            // 0..31
  const int nt = inner & 1;            // n-tile twins of a j-tile share an XCD
  const int jt = xcd + ((inner >> 1) << 3);   // 0..127
  const int n0 = nt * 256, j0 = jt * 256;
  const int t = threadIdx.x, wv = t >> 6, l = t & 63;
  const int wm = wv >> 2, wj = wv & 3; // 2(m) x 4(j) wave grid; wave = 128n x 64j

// stage K-step KS_ into buffer BUF_: 4 gload_lds per thread (2 A + 2 B)
#define STAGE(KS_, BUF_) {                                                     \
    const int k0_ = (KS_) * 32;                                                \
    const ushort_t* As_ = sums_bf + (size_t)(n0 + wv * 16 + (l & 15)) * 768 +  \
                          k0_ + (l >> 4) * 8;                                  \
    const ushort_t* Bs_ = xbf + (size_t)(j0 + wv * 16 + (l & 15)) * 768 +      \
                          k0_ + (l >> 4) * 8;                                  \
    __builtin_amdgcn_global_load_lds(GPTR(As_),                                \
        LPTR(&lds[BUF_][wv * 512]), 16, 0, 0);                                 \
    __builtin_amdgcn_global_load_lds(GPTR(As_ + (size_t)128 * 768),            \
        LPTR(&lds[BUF_][(wv + 8) * 512]), 16, 0, 0);                           \
    __builtin_amdgcn_global_load_lds(GPTR(Bs_),                                \
        LPTR(&lds[BUF_][8192 + wv * 512]), 16, 0, 0);                          \
    __builtin_amdgcn_global_load_lds(GPTR(Bs_ + (size_t)128 * 768),            \
        LPTR(&lds[BUF_][8192 + (wv + 8) * 512]), 16, 0, 0);                    \
  }

  floatx4 acc[8][4];
#pragma unroll
  for (int mi = 0; mi < 8; ++mi)
#pragma unroll
    for (int ni = 0; ni < 4; ++ni) acc[mi][ni] = (floatx4){0.f, 0.f, 0.f, 0.f};

  STAGE(0, 0)
  STAGE(1, 1)
  STAGE(2, 2)                          // 12 loads/thread outstanding

  for (int kb = 0; kb < 24; ++kb) {
    if (kb < 22)       { asm volatile("s_waitcnt vmcnt(8)" ::: "memory"); }
    else if (kb == 22) { asm volatile("s_waitcnt vmcnt(4)" ::: "memory"); }
    else               { asm volatile("s_waitcnt vmcnt(0)" ::: "memory"); }
    __builtin_amdgcn_s_barrier();
    __builtin_amdgcn_sched_barrier(0);
    const int cb = kb & 3, sb = (kb + 3) & 3;

    short8 af[8], bf[4];
#pragma unroll
    for (int mi = 0; mi < 8; ++mi)
      af[mi] = *(const short8*)&lds[cb][(wm * 8 + mi) * 512 + l * 8];
#pragma unroll
    for (int ni = 0; ni < 4; ++ni)
      bf[ni] = *(const short8*)&lds[cb][8192 + (wj * 4 + ni) * 512 + l * 8];
    if (kb + 3 < 24) STAGE(kb + 3, sb)
    asm volatile("s_waitcnt lgkmcnt(0)" ::: "memory");
    __builtin_amdgcn_sched_barrier(0);
    __builtin_amdgcn_s_setprio(1);
#pragma unroll
    for (int mi = 0; mi < 8; ++mi)
#pragma unroll
      for (int ni = 0; ni < 4; ++ni)
        acc[mi][ni] = __builtin_amdgcn_mfma_f32_16x16x32_bf16(
            af[mi], bf[ni], acc[mi][ni], 0, 0, 0);
    __builtin_amdgcn_s_setprio(0);
  }

  // ---- epilogue: S = acc * rcn[n] * rxn[j] + b ; colsum += exp(S); diag sx.
  const float bb = *bp;
  float rxv[4], p[4] = {0.f, 0.f, 0.f, 0.f};
#pragma unroll
  for (int ni = 0; ni < 4; ++ni)
    rxv[ni] = rxn[j0 + wj * 64 + ni * 16 + (l & 15)];
  const bool diagblk = (nt == (jt >> 6));

#pragma unroll
  for (int mi = 0; mi < 8; ++mi) {
    float4 rr = *(const float4*)&rcn[n0 + wm * 128 + mi * 16 + ((l >> 4) << 2)];
    const float rc[4] = {rr.x, rr.y, rr.z, rr.w};
#pragma unroll
    for (int ni = 0; ni < 4; ++ni) {
      floatx4 a = acc[mi][ni];
#pragma unroll
      for (int q = 0; q < 4; ++q)
        p[ni] += __expf(a[q] * rc[q] * rxv[ni] + bb);
      if (diagblk) {
        const int jg = j0 + wj * 64 + ni * 16 + (l & 15);
#pragma unroll
        for (int q = 0; q < 4; ++q) {
          const int mg = n0 + wm * 128 + mi * 16 + ((l >> 4) << 2) + q;
          if (mg == (jg >> 6)) sdiag_dot[jg] = a[q];
        }
      }
    }
  }
#pragma unroll
  for (int ni = 0; ni < 4; ++ni) {
    p[ni] += __shfl_xor(p[ni], 16, 64);
    p[ni] += __shfl_xor(p[ni], 32, 64);
  }
  if (l < 16) {
#pragma unroll
    for (int ni = 0; ni < 4; ++ni)
      atomicAdd(&colsum[j0 + wj * 64 + ni * 16 + l], p[ni]);
  }
}

// ---- kD: per-sample loss from colsum + diagonal dot, reduce to scalar -----
__global__ __launch_bounds__(256) void kD(const float* __restrict__ colsum,
    const float* __restrict__ sdiag_dot, const float* __restrict__ xx,
    const float* __restrict__ ss, const float* __restrict__ rcn,
    const float* __restrict__ wp, const float* __restrict__ bp,
    float* __restrict__ out) {
  const int j = blockIdx.x * 256 + threadIdx.x;
  const int i = j >> 6;
  const float ww = *wp, bb = *bp;
  const float sx = sdiag_dot[j];
  const float xxv = xx[j];
  const float xn = fmaxf(sqrtf(xxv), EPS);
  const float rx = 1.0f / xn;
  const float sd = sx * rcn[i] * rx + bb;                         // S_diag
  const float exn = sqrtf(fmaxf(ss[i] - 2.f * sx + xxv, 0.f)) * (1.f / 63.f);
  const float edot = (sx - xxv) * (1.f / 63.f);
  const float sm = ww * edot / (fmaxf(exn, EPS) * xn) + bb;       // S_same
  const float tot = colsum[j] - __expf(sd) + __expf(sm);
  float L = -sm + logf(fmaxf(tot, 1e-30f));
  for (int o = 32; o; o >>= 1) L += __shfl_xor(L, o, 64);
  __shared__ float red[4];
  if ((threadIdx.x & 63) == 0) red[threadIdx.x >> 6] = L;
  __syncthreads();
  if (threadIdx.x == 0) atomicAdd(out, red[0] + red[1] + red[2] + red[3]);
}

extern "C" void kernel_launch(void* const* d_in, const int* in_sizes, int n_in,
                              void* d_out, int out_size, void* d_ws, size_t ws_size,
                              hipStream_t stream) {
  const float* x  = (const float*)d_in[0];
  const float* wp = (const float*)d_in[1];
  const float* bp = (const float*)d_in[2];
  float* out = (float*)d_out;

  // ws layout (float offsets):
  float* fws = (float*)d_ws;
  float* ss        = fws;             // 512
  float* rcn       = fws + 512;       // 512
  float* xx        = fws + 1024;      // 32768
  float* rxn       = fws + 33792;     // 32768
  float* colsum    = fws + 66560;     // 32768
  float* sdiag_dot = fws + 99328;     // 32768
  ushort_t* sums_bf = (ushort_t*)(fws + 132096);   // 393216 ushorts
  ushort_t* xbf     = (ushort_t*)(fws + 328704);   // 25165824 ushorts
  // total = 12911616 floats ~= 49.3 MiB

  hipMemsetAsync(colsum, 0, 32768 * sizeof(float), stream);
  hipMemsetAsync(out, 0, sizeof(float), stream);

  kA<<<512, 256, 0, stream>>>(x, xbf, sums_bf, ss, rcn, xx, rxn, wp);
  kC<<<256, 512, 0, stream>>>(xbf, sums_bf, rcn, rxn, colsum, sdiag_dot, bp);
  kD<<<128, 256, 0, stream>>>(colsum, sdiag_dot, xx, ss, rcn, wp, bp, out);
}